// Round 1
// baseline (667.592 us; speedup 1.0000x reference)
//
#include <hip/hip_runtime.h>
#include <hip/hip_bf16.h>
#include <cstdint>
#include <cstddef>

#define NB   16      // batch
#define LQ   128
#define LK   4096
#define DD   1024

typedef float f32x4  __attribute__((ext_vector_type(4)));
typedef int   i32x4  __attribute__((ext_vector_type(4)));
typedef short bf16x8 __attribute__((ext_vector_type(8)));

static __device__ __forceinline__ short f2bf(float x) {
  __bf16 h = (__bf16)x;                 // compiler emits v_cvt_pk_bf16_f32 pairs (m240)
  return __builtin_bit_cast(short, h);
}

// ---------------- K1: S[b,q,k] = dot(xs[b,q,:], ys[b,k,:]) / 32  (raw, unmasked) ----
// grid (32, 16), 256 thr. Block tile 128(M=all Lq) x 128(keys). LDS-free: frags
// straight from global (both operands contraction-fast => 8 contiguous f32/lane).
__global__ __launch_bounds__(256, 2) void k_scores(
    const float* __restrict__ xs, const float* __restrict__ ys,
    float* __restrict__ S) {
  const int b    = blockIdx.y;
  const int nbk  = blockIdx.x;                 // key-block of 128
  const int tid  = threadIdx.x;
  const int lane = tid & 63, w = tid >> 6;
  const int wr = w >> 1, wc = w & 1;           // 2x2 wave grid, 64x64 per wave
  const int l15 = lane & 15, lg = lane >> 4;

  const float* A  = xs + (size_t)b * LQ * DD;  // [128][1024]
  const float* Bt = ys + (size_t)b * LK * DD;  // [4096][1024]

  int mrow[4], nrow[4];
  #pragma unroll
  for (int i = 0; i < 4; ++i) {
    mrow[i] = wr * 64 + i * 16 + l15;
    nrow[i] = nbk * 128 + wc * 64 + i * 16 + l15;
  }

  f32x4 acc[4][4] = {};

  for (int k0 = 0; k0 < DD; k0 += 32) {
    const int kf = k0 + lg * 8;
    bf16x8 af[4], bfr[4];
    #pragma unroll
    for (int i = 0; i < 4; ++i) {
      const float* p = A + (size_t)mrow[i] * DD + kf;
      f32x4 x0 = *(const f32x4*)p;
      f32x4 x1 = *(const f32x4*)(p + 4);
      #pragma unroll
      for (int t = 0; t < 4; ++t) { af[i][t] = f2bf(x0[t]); af[i][4 + t] = f2bf(x1[t]); }
    }
    #pragma unroll
    for (int i = 0; i < 4; ++i) {
      const float* p = Bt + (size_t)nrow[i] * DD + kf;
      f32x4 x0 = *(const f32x4*)p;
      f32x4 x1 = *(const f32x4*)(p + 4);
      #pragma unroll
      for (int t = 0; t < 4; ++t) { bfr[i][t] = f2bf(x0[t]); bfr[i][4 + t] = f2bf(x1[t]); }
    }
    #pragma unroll
    for (int mi = 0; mi < 4; ++mi)
      #pragma unroll
      for (int ni = 0; ni < 4; ++ni)
        acc[mi][ni] = __builtin_amdgcn_mfma_f32_16x16x32_bf16(af[mi], bfr[ni], acc[mi][ni], 0, 0, 0);
  }

  const float scale = 0.03125f;                // 1/sqrt(1024), exact pow2
  #pragma unroll
  for (int mi = 0; mi < 4; ++mi)
    #pragma unroll
    for (int ni = 0; ni < 4; ++ni) {
      const int q  = wr * 64 + mi * 16 + lg * 4;          // D layout: row=(lane>>4)*4+r
      const int kc = nbk * 128 + wc * 64 + ni * 16 + l15; // col = lane&15
      float* o = S + ((size_t)b * LQ + q) * LK + kc;
      #pragma unroll
      for (int r = 0; r < 4; ++r) o[(size_t)r * LK] = acc[mi][ni][r] * scale;
    }
}

// ---------------- K2: in-place masked softmax over each row of S ----------------
// grid 2048 (one block per (b,q) row), 256 thr, 16 elems/thread held in registers.
__device__ __forceinline__ float wred_max(float v) {
  #pragma unroll
  for (int off = 32; off > 0; off >>= 1) v = fmaxf(v, __shfl_xor(v, off, 64));
  return v;
}
__device__ __forceinline__ float wred_sum(float v) {
  #pragma unroll
  for (int off = 32; off > 0; off >>= 1) v += __shfl_xor(v, off, 64);
  return v;
}

__global__ __launch_bounds__(256) void k_softmax(
    float* __restrict__ S, const int* __restrict__ mask) {
  const int row = blockIdx.x;            // b*128 + q
  const int b   = row >> 7;
  float* Srow = S + (size_t)row * LK;
  const int* Mrow = mask + b * LK;
  const int tid = threadIdx.x;
  const int lane = tid & 63, w = tid >> 6;

  __shared__ float red[4];

  float v[16];
  float lmax = -INFINITY;
  #pragma unroll
  for (int j = 0; j < 4; ++j) {
    const int c4 = tid + 256 * j;
    f32x4 s = ((const f32x4*)Srow)[c4];
    i32x4 m = ((const i32x4*)Mrow)[c4];
    #pragma unroll
    for (int t = 0; t < 4; ++t) {
      float val = (m[t] != 0) ? s[t] : -INFINITY;
      v[j * 4 + t] = val;
      lmax = fmaxf(lmax, val);
    }
  }
  float wm = wred_max(lmax);
  if (lane == 0) red[w] = wm;
  __syncthreads();
  const float mrow_max = fmaxf(fmaxf(red[0], red[1]), fmaxf(red[2], red[3]));
  __syncthreads();                       // red reuse barrier

  float lsum = 0.f;
  #pragma unroll
  for (int i = 0; i < 16; ++i) {
    v[i] = __expf(v[i] - mrow_max);      // exp(-inf)=0 handles masked lanes
    lsum += v[i];
  }
  float wsum = wred_sum(lsum);
  if (lane == 0) red[w] = wsum;
  __syncthreads();
  const float Z = red[0] + red[1] + red[2] + red[3];
  const float inv = 1.0f / Z;

  #pragma unroll
  for (int j = 0; j < 4; ++j) {
    f32x4 o;
    #pragma unroll
    for (int t = 0; t < 4; ++t) o[t] = v[j * 4 + t] * inv;
    ((f32x4*)Srow)[tid + 256 * j] = o;
  }
}

// ---------------- K3: emb[b,q,d] = sum_k P[b,q,k] * ys[b,k,d] ----------------
// grid (32, 16), 256 thr. Block tile 128(M) x 32(d). Waves stacked on M (32 rows
// each) so all 4 waves share the same Y columns (L1 reuse). Y frag = 8 scalar
// loads (contraction is Y's slow dim); P frags contiguous.
__global__ __launch_bounds__(256, 2) void k_pv(
    const float* __restrict__ P, const float* __restrict__ ys,
    float* __restrict__ emb) {
  const int b  = blockIdx.y;
  const int nb = blockIdx.x;             // d-block of 32
  const int tid = threadIdx.x;
  const int lane = tid & 63, w = tid >> 6;
  const int l15 = lane & 15, lg = lane >> 4;

  const float* Pb = P  + (size_t)b * LQ * LK;  // [128][4096]
  const float* Y  = ys + (size_t)b * LK * DD;  // [4096][1024]

  int mrow[2], ncol[2];
  #pragma unroll
  for (int i = 0; i < 2; ++i) {
    mrow[i] = w * 32 + i * 16 + l15;
    ncol[i] = nb * 32 + i * 16 + l15;
  }

  f32x4 acc[2][2] = {};

  for (int k0 = 0; k0 < LK; k0 += 32) {
    const int kf = k0 + lg * 8;
    bf16x8 af[2], bfr[2];
    #pragma unroll
    for (int i = 0; i < 2; ++i) {
      const float* p = Pb + (size_t)mrow[i] * LK + kf;
      f32x4 x0 = *(const f32x4*)p;
      f32x4 x1 = *(const f32x4*)(p + 4);
      #pragma unroll
      for (int t = 0; t < 4; ++t) { af[i][t] = f2bf(x0[t]); af[i][4 + t] = f2bf(x1[t]); }
    }
    #pragma unroll
    for (int i = 0; i < 2; ++i) {
      #pragma unroll
      for (int j = 0; j < 8; ++j)
        bfr[i][j] = f2bf(Y[(size_t)(kf + j) * DD + ncol[i]]);
    }
    #pragma unroll
    for (int mi = 0; mi < 2; ++mi)
      #pragma unroll
      for (int ni = 0; ni < 2; ++ni)
        acc[mi][ni] = __builtin_amdgcn_mfma_f32_16x16x32_bf16(af[mi], bfr[ni], acc[mi][ni], 0, 0, 0);
  }

  #pragma unroll
  for (int mi = 0; mi < 2; ++mi)
    #pragma unroll
    for (int ni = 0; ni < 2; ++ni) {
      const int q = w * 32 + mi * 16 + lg * 4;
      const int d = nb * 32 + ni * 16 + l15;
      float* o = emb + ((size_t)b * LQ + q) * DD + d;
      #pragma unroll
      for (int r = 0; r < 4; ++r) o[(size_t)r * DD] = acc[mi][ni][r];
    }
}

extern "C" void kernel_launch(void* const* d_in, const int* in_sizes, int n_in,
                              void* d_out, int out_size, void* d_ws, size_t ws_size,
                              hipStream_t stream) {
  const float* xs   = (const float*)d_in[0];   // [16][128][1024] f32
  const float* ys   = (const float*)d_in[1];   // [16][4096][1024] f32
  const int*   mask = (const int*)d_in[2];     // [16][4096] i32 (0/1)

  float* emb = (float*)d_out;                          // [16][128][1024]
  float* S   = emb + (size_t)NB * LQ * DD;             // [16][128][4096] (l2 region)

  k_scores <<<dim3(LK / 128, NB), 256, 0, stream>>>(xs, ys, S);
  k_softmax<<<NB * LQ,            256, 0, stream>>>(S, mask);
  k_pv     <<<dim3(DD / 32, NB),  256, 0, stream>>>(S, ys, emb);
}

// Round 2
// 486.540 us; speedup vs baseline: 1.3721x; 1.3721x over previous
//
#include <hip/hip_runtime.h>
#include <hip/hip_bf16.h>
#include <cstdint>
#include <cstddef>

#define NB   16
#define LQ   128
#define LK   4096
#define DD   1024

typedef float f32x4  __attribute__((ext_vector_type(4)));
typedef short bf16x4 __attribute__((ext_vector_type(4)));
typedef short bf16x8 __attribute__((ext_vector_type(8)));

static __device__ __forceinline__ short f2bf(float x) {
  __bf16 h = (__bf16)x;
  return __builtin_bit_cast(short, h);
}

// =====================================================================
// K1: S[b,q,k] = masked( dot(xs[b,q,:], ys[b,k,:]) / 32 )
// tile 128q x 64k, BK=64 over D, dbuf LDS (bf16, XOR-swizzled), 1 barrier/iter
// grid 1024 = 64 kblocks x 16 b, XCD-chunked (2 batches per XCD)
// =====================================================================
__global__ __launch_bounds__(256, 3) void k_scores(
    const float* __restrict__ xs, const float* __restrict__ ys,
    const int* __restrict__ mask, float* __restrict__ S) {
  const int n = blockIdx.x;
  const int orig = (n & 7) * 128 + (n >> 3);     // nwg=1024, bijective
  const int b  = orig >> 6;
  const int kb = orig & 63;

  const int tid = threadIdx.x;
  const int lane = tid & 63, w = tid >> 6;
  const int wm = (w >> 1) * 64, wn = (w & 1) * 32;   // wave tile 64x32
  const int l15 = lane & 15, lg = lane >> 4;

  const float* A = xs + (size_t)b * (LQ * DD);                 // [128][1024]
  const float* B = ys + ((size_t)b * LK + (size_t)kb * 64) * DD; // [64][1024]

  // per buffer: A 128 rows x 128B, B 64 rows x 128B (bf16)
  __shared__ short lds[2][(128 + 64) * 64];

  f32x4 ga[8], gb[4];

  auto issue = [&](int t) {
    const int koff = t * 64;
    #pragma unroll
    for (int r = 0; r < 8; ++r) {
      const int id = r * 256 + tid;
      ga[r] = *(const f32x4*)(A + (size_t)(id >> 4) * DD + koff + (id & 15) * 4);
    }
    #pragma unroll
    for (int r = 0; r < 4; ++r) {
      const int id = r * 256 + tid;
      gb[r] = *(const f32x4*)(B + (size_t)(id >> 4) * DD + koff + (id & 15) * 4);
    }
  };

  auto stash = [&](int buf) {
    char* base = (char*)&lds[buf][0];
    #pragma unroll
    for (int r = 0; r < 8; ++r) {
      const int id = r * 256 + tid;
      const int row = id >> 4, c4 = id & 15;
      const int byte = (row * 128 + c4 * 8) ^ ((row & 7) << 4);
      bf16x4 v;
      v[0] = f2bf(ga[r][0]); v[1] = f2bf(ga[r][1]);
      v[2] = f2bf(ga[r][2]); v[3] = f2bf(ga[r][3]);
      *(bf16x4*)(base + byte) = v;
    }
    char* bb = (char*)&lds[buf][128 * 64];
    #pragma unroll
    for (int r = 0; r < 4; ++r) {
      const int id = r * 256 + tid;
      const int row = id >> 4, c4 = id & 15;
      const int byte = (row * 128 + c4 * 8) ^ ((row & 7) << 4);
      bf16x4 v;
      v[0] = f2bf(gb[r][0]); v[1] = f2bf(gb[r][1]);
      v[2] = f2bf(gb[r][2]); v[3] = f2bf(gb[r][3]);
      *(bf16x4*)(bb + byte) = v;
    }
  };

  f32x4 acc[4][2] = {};

  issue(0);
  stash(0);
  __syncthreads();

  for (int t = 0; t < 16; ++t) {
    const char* base = (const char*)&lds[t & 1][0];
    const char* bbase = (const char*)&lds[t & 1][128 * 64];
    if (t + 1 < 16) issue(t + 1);
    #pragma unroll
    for (int kk = 0; kk < 2; ++kk) {
      bf16x8 af[4], bfr[2];
      #pragma unroll
      for (int mi = 0; mi < 4; ++mi) {
        const int row = wm + mi * 16 + l15;
        const int byte = (row * 128 + kk * 64 + lg * 16) ^ ((row & 7) << 4);
        af[mi] = *(const bf16x8*)(base + byte);
      }
      #pragma unroll
      for (int ni = 0; ni < 2; ++ni) {
        const int row = wn + ni * 16 + l15;
        const int byte = (row * 128 + kk * 64 + lg * 16) ^ ((row & 7) << 4);
        bfr[ni] = *(const bf16x8*)(bbase + byte);
      }
      #pragma unroll
      for (int mi = 0; mi < 4; ++mi)
        #pragma unroll
        for (int ni = 0; ni < 2; ++ni)
          acc[mi][ni] = __builtin_amdgcn_mfma_f32_16x16x32_bf16(af[mi], bfr[ni], acc[mi][ni], 0, 0, 0);
    }
    if (t + 1 < 16) stash((t + 1) & 1);
    __syncthreads();
  }

  // epilogue: scale + mask + store
  const int* mrow = mask + b * LK + kb * 64;
  int mk[2];
  #pragma unroll
  for (int ni = 0; ni < 2; ++ni) mk[ni] = mrow[wn + ni * 16 + l15];
  float* Srow = S + (size_t)b * LQ * LK + (size_t)kb * 64;
  #pragma unroll
  for (int mi = 0; mi < 4; ++mi)
    #pragma unroll
    for (int ni = 0; ni < 2; ++ni) {
      const int q  = wm + mi * 16 + lg * 4;
      const int kc = wn + ni * 16 + l15;
      float* o = Srow + (size_t)q * LK + kc;
      #pragma unroll
      for (int r = 0; r < 4; ++r)
        o[(size_t)r * LK] = mk[ni] ? acc[mi][ni][r] * 0.03125f : -1e30f;
    }
}

// =====================================================================
// K2: in-place row softmax (S already masked with -1e30 -> exp underflows to 0)
// =====================================================================
__device__ __forceinline__ float wred_max(float v) {
  #pragma unroll
  for (int off = 32; off > 0; off >>= 1) v = fmaxf(v, __shfl_xor(v, off, 64));
  return v;
}
__device__ __forceinline__ float wred_sum(float v) {
  #pragma unroll
  for (int off = 32; off > 0; off >>= 1) v += __shfl_xor(v, off, 64);
  return v;
}

__global__ __launch_bounds__(256) void k_softmax(float* __restrict__ S) {
  const int row = blockIdx.x;                    // b*128 + q
  float* Srow = S + (size_t)row * LK;
  const int tid = threadIdx.x;
  const int lane = tid & 63, w = tid >> 6;
  __shared__ float red[4];

  float v[16];
  float lmax = -INFINITY;
  #pragma unroll
  for (int j = 0; j < 4; ++j) {
    f32x4 s = ((const f32x4*)Srow)[tid + 256 * j];
    #pragma unroll
    for (int t = 0; t < 4; ++t) { v[j * 4 + t] = s[t]; lmax = fmaxf(lmax, s[t]); }
  }
  float wmx = wred_max(lmax);
  if (lane == 0) red[w] = wmx;
  __syncthreads();
  const float m = fmaxf(fmaxf(red[0], red[1]), fmaxf(red[2], red[3]));
  __syncthreads();

  float lsum = 0.f;
  #pragma unroll
  for (int i = 0; i < 16; ++i) { v[i] = __expf(v[i] - m); lsum += v[i]; }
  float wsm = wred_sum(lsum);
  if (lane == 0) red[w] = wsm;
  __syncthreads();
  const float inv = 1.0f / (red[0] + red[1] + red[2] + red[3]);

  #pragma unroll
  for (int j = 0; j < 4; ++j) {
    f32x4 o;
    #pragma unroll
    for (int t = 0; t < 4; ++t) o[t] = v[j * 4 + t] * inv;
    ((f32x4*)Srow)[tid + 256 * j] = o;
  }
}

// =====================================================================
// K3: partial emb = P[b, :, khalf] * ys[b, khalf, dtile]
// tile 128q x 64d, BK=64 over k, NT=32; ys transpose-staged [d][k] in LDS
// grid 512 = 16 dt x 2 kh x 16 b, XCD-chunked (2 batches per XCD)
// kh==0 writes emb directly, kh==1 writes ws partial
// =====================================================================
__global__ __launch_bounds__(256, 2) void k_pv(
    const float* __restrict__ P, const float* __restrict__ ys,
    float* __restrict__ emb, float* __restrict__ part) {
  const int n = blockIdx.x;
  const int orig = (n & 7) * 64 + (n >> 3);      // nwg=512, bijective
  const int b  = orig >> 5;
  const int kh = (orig >> 4) & 1;
  const int dt = orig & 15;

  const int tid = threadIdx.x;
  const int lane = tid & 63, w = tid >> 6;
  const int wm = (w >> 1) * 64, wn = (w & 1) * 32;
  const int l15 = lane & 15, lg = lane >> 4;

  const float* Pb = P  + (size_t)b * LQ * LK + (size_t)kh * 2048;
  const float* Y  = ys + ((size_t)b * LK + (size_t)kh * 2048) * DD + dt * 64;

  // per buffer: A(P) 128 rows x 128B, B(Y^T) 64 d-rows x 128B
  __shared__ short lds[2][(128 + 64) * 64];

  f32x4 ga[8], gb[4];

  auto issue = [&](int t) {
    const int k0 = t * 64;
    #pragma unroll
    for (int r = 0; r < 8; ++r) {
      const int id = r * 256 + tid;
      ga[r] = *(const f32x4*)(Pb + (size_t)(id >> 4) * LK + k0 + (id & 15) * 4);
    }
    #pragma unroll
    for (int r = 0; r < 4; ++r) {
      const int id = r * 256 + tid;      // krow = id>>4 (64), dc4 = id&15 (16 x 4d)
      gb[r] = *(const f32x4*)(Y + (size_t)(k0 + (id >> 4)) * DD + (id & 15) * 4);
    }
  };

  auto stash = [&](int buf) {
    char* base = (char*)&lds[buf][0];
    #pragma unroll
    for (int r = 0; r < 8; ++r) {
      const int id = r * 256 + tid;
      const int row = id >> 4, c4 = id & 15;
      const int byte = (row * 128 + c4 * 8) ^ ((row & 7) << 4);
      bf16x4 v;
      v[0] = f2bf(ga[r][0]); v[1] = f2bf(ga[r][1]);
      v[2] = f2bf(ga[r][2]); v[3] = f2bf(ga[r][3]);
      *(bf16x4*)(base + byte) = v;
    }
    char* bb = (char*)&lds[buf][128 * 64];
    #pragma unroll
    for (int r = 0; r < 4; ++r) {
      const int id = r * 256 + tid;
      const int krow = id >> 4, dc4 = id & 15;
      #pragma unroll
      for (int j = 0; j < 4; ++j) {
        const int d = dc4 * 4 + j;
        const int byte = (d * 128 + krow * 2) ^ ((d & 7) << 4);
        *(short*)(bb + byte) = f2bf(gb[r][j]);
      }
    }
  };

  f32x4 acc[4][2] = {};

  issue(0);
  stash(0);
  __syncthreads();

  for (int t = 0; t < 32; ++t) {
    const char* base  = (const char*)&lds[t & 1][0];
    const char* bbase = (const char*)&lds[t & 1][128 * 64];
    if (t + 1 < 32) issue(t + 1);
    #pragma unroll
    for (int kk = 0; kk < 2; ++kk) {
      bf16x8 af[4], bfr[2];
      #pragma unroll
      for (int mi = 0; mi < 4; ++mi) {
        const int row = wm + mi * 16 + l15;
        const int byte = (row * 128 + kk * 64 + lg * 16) ^ ((row & 7) << 4);
        af[mi] = *(const bf16x8*)(base + byte);
      }
      #pragma unroll
      for (int ni = 0; ni < 2; ++ni) {
        const int d = wn + ni * 16 + l15;
        const int byte = (d * 128 + kk * 64 + lg * 16) ^ ((d & 7) << 4);
        bfr[ni] = *(const bf16x8*)(bbase + byte);
      }
      #pragma unroll
      for (int mi = 0; mi < 4; ++mi)
        #pragma unroll
        for (int ni = 0; ni < 2; ++ni)
          acc[mi][ni] = __builtin_amdgcn_mfma_f32_16x16x32_bf16(af[mi], bfr[ni], acc[mi][ni], 0, 0, 0);
    }
    if (t + 1 < 32) stash((t + 1) & 1);
    __syncthreads();
  }

  float* dst = (kh == 0 ? emb : part) + (size_t)b * LQ * DD + dt * 64;
  #pragma unroll
  for (int mi = 0; mi < 4; ++mi)
    #pragma unroll
    for (int ni = 0; ni < 2; ++ni) {
      const int q = wm + mi * 16 + lg * 4;
      const int d = wn + ni * 16 + l15;
      float* o = dst + (size_t)q * DD + d;
      #pragma unroll
      for (int r = 0; r < 4; ++r) o[(size_t)r * DD] = acc[mi][ni][r];
    }
}

// =====================================================================
// K4: emb += partial (k-split reduction)
// =====================================================================
__global__ __launch_bounds__(256) void k_add(float* __restrict__ emb,
                                             const float* __restrict__ part) {
  const size_t i = (size_t)blockIdx.x * 256 + threadIdx.x;  // f32x4 index
  f32x4 a = ((const f32x4*)emb)[i];
  f32x4 p = ((const f32x4*)part)[i];
  ((f32x4*)emb)[i] = a + p;
}

extern "C" void kernel_launch(void* const* d_in, const int* in_sizes, int n_in,
                              void* d_out, int out_size, void* d_ws, size_t ws_size,
                              hipStream_t stream) {
  const float* xs   = (const float*)d_in[0];   // [16][128][1024] f32
  const float* ys   = (const float*)d_in[1];   // [16][4096][1024] f32
  const int*   mask = (const int*)d_in[2];     // [16][4096] i32

  float* emb  = (float*)d_out;                       // [16][128][1024]
  float* S    = emb + (size_t)NB * LQ * DD;          // [16][128][4096] (l2 out)
  float* part = (float*)d_ws;                        // [16][128][1024] partial (8 MB)

  k_scores <<<1024, 256, 0, stream>>>(xs, ys, mask, S);
  k_softmax<<<NB * LQ, 256, 0, stream>>>(S);
  k_pv     <<<512, 256, 0, stream>>>(S, ys, emb, part);
  k_add    <<<(NB * LQ * DD / 4) / 256, 256, 0, stream>>>(emb, part);
}